// Round 2
// baseline (1869.790 us; speedup 1.0000x reference)
//
#include <hip/hip_runtime.h>

// CrossModalHyperedgeInteraction: 3-modality cross-attention, MI355X bf16-MFMA impl.
// R1: identical to R0 (bench failed on infra, no signal). ws: Wbf(2MB) | Qb | Kb | Vt (bf16).
// D=512, B=32, K={1024,768,512}, tokOff={0,32768,57344}, total tokens 73728.

typedef unsigned short u16;
typedef unsigned int   u32;
typedef __attribute__((ext_vector_type(8))) short vbf8;   // 8 bf16 (4 VGPR) MFMA A/B frag
typedef __attribute__((ext_vector_type(4))) float vf4;    // MFMA C/D frag

#define MFMA(a,b,c) __builtin_amdgcn_mfma_f32_16x16x32_bf16(a,b,c,0,0,0)

__device__ __forceinline__ u16 f2bf(float f){
  u32 x = __float_as_uint(f);
  return (u16)((x + 0x7fffu + ((x >> 16) & 1u)) >> 16);   // RNE bf16
}

// ---------------- kernel 1: W fp32 -> bf16 (4 weights, 512x512 each) ----------------
__global__ void wconv_k(const float* __restrict__ Wq, const float* __restrict__ Wk,
                        const float* __restrict__ Wv, const float* __restrict__ Wo,
                        u16* __restrict__ Wbf){
  int i = blockIdx.x * 256 + threadIdx.x;            // 0..262143, 4 floats each
  int w = i >> 16;
  int off = (i & 65535) << 2;
  const float* src = (w == 0) ? Wq : (w == 1) ? Wk : (w == 2) ? Wv : Wo;
  float4 v = *(const float4*)(src + off);
  u32 lo = (u32)f2bf(v.x) | ((u32)f2bf(v.y) << 16);
  u32 hi = (u32)f2bf(v.z) | ((u32)f2bf(v.w) << 16);
  uint2 p; p.x = lo; p.y = hi;
  *(uint2*)(Wbf + (w << 18) + off) = p;
}

// ---------------- kernel 2: projections C = E*W^T + b ----------------
// grid (512, 4 weights, 3 modalities), block 256 (4 waves, 16 rows each, 512 cols).
// z-outputs: widx 0->Qb (scaled 1/sqrt(512)), 1->Kb, 2->Vt (transposed), 3->Oproj fp32 in d_out.
__global__ void __launch_bounds__(256) proj_k(
    const float* __restrict__ E0, const float* __restrict__ E1, const float* __restrict__ E2,
    const u16* __restrict__ Wbf,
    const float* __restrict__ bq, const float* __restrict__ bk,
    const float* __restrict__ bv, const float* __restrict__ bo,
    u16* __restrict__ Qb, u16* __restrict__ Kb, u16* __restrict__ Vtb,
    float* __restrict__ outF)
{
  const int mod = blockIdx.z, widx = blockIdx.y, xt = blockIdx.x;
  const int Km   = (mod == 0) ? 1024 : (mod == 1) ? 768 : 512;
  const int Mmod = Km * 32;
  if (xt * 64 >= Mmod) return;
  const int tokOff = (mod == 0) ? 0 : (mod == 1) ? 32768 : 57344;
  const float* E = (mod == 0) ? E0 : (mod == 1) ? E1 : E2;
  const u16* W = Wbf + (widx << 18);
  const float* bias = (widx == 0) ? bq : (widx == 1) ? bk : (widx == 2) ? bv : bo;

  __shared__ __align__(16) char smem[36864];   // Elds [64][32] @0 (4KB) | Wlds [512][32] @4096 (32KB)

  const int tid = threadIdx.x;
  const int wv = tid >> 6, l = tid & 63, g = l >> 4, c = l & 15;

  vf4 acc[32];
  #pragma unroll
  for (int ch = 0; ch < 32; ++ch) acc[ch] = (vf4){0.f, 0.f, 0.f, 0.f};

  for (int kt = 0; kt < 16; ++kt){
    { // stage E tile (convert fp32->bf16): 64 rows x 4 slots of 16B
      int row = tid >> 2, sl = tid & 3;
      const float* s = E + (size_t)(xt * 64 + row) * 512 + kt * 32 + sl * 8;
      float4 aa = *(const float4*)s;
      float4 bb = *(const float4*)(s + 4);
      int4 p;
      p.x = (int)((u32)f2bf(aa.x) | ((u32)f2bf(aa.y) << 16));
      p.y = (int)((u32)f2bf(aa.z) | ((u32)f2bf(aa.w) << 16));
      p.z = (int)((u32)f2bf(bb.x) | ((u32)f2bf(bb.y) << 16));
      p.w = (int)((u32)f2bf(bb.z) | ((u32)f2bf(bb.w) << 16));
      *(int4*)(smem + row * 64 + ((sl * 16) ^ ((row & 3) << 4))) = p;
    }
    // stage W tile: 512 rows x 4 slots of 16B (already bf16)
    #pragma unroll
    for (int it = 0; it < 8; ++it){
      int flat = it * 256 + tid;
      int row = flat >> 2, sl = flat & 3;
      int4 v = *(const int4*)(W + row * 512 + kt * 32 + sl * 8);
      *(int4*)(smem + 4096 + row * 64 + ((sl * 16) ^ ((row & 3) << 4))) = v;
    }
    __syncthreads();
    const int arow = wv * 16 + c;
    vbf8 af = *(const vbf8*)(smem + arow * 64 + ((g * 16) ^ ((arow & 3) << 4)));
    #pragma unroll
    for (int ch = 0; ch < 32; ++ch){
      int e = ch * 16 + c;
      vbf8 bf = *(const vbf8*)(smem + 4096 + e * 64 + ((g * 16) ^ ((e & 3) << 4)));
      acc[ch] = MFMA(af, bf, acc[ch]);
    }
    __syncthreads();
  }

  const float scale = (widx == 0) ? 0.04419417382415922f : 1.0f;   // 1/sqrt(512) folded into Q

  if (widx == 2){
    // V: write transposed Vt[mod][b][e=512][Km] via LDS transpose (stride-65 pad)
    const int b = (xt * 64) / Km, tokl = (xt * 64) % Km;
    u16* T = (u16*)smem;                                   // [256 e][65]
    const size_t vbase = (size_t)tokOff * 512 + (size_t)b * 512 * Km + tokl;
    for (int h = 0; h < 2; ++h){
      __syncthreads();
      #pragma unroll
      for (int ch = 0; ch < 16; ++ch){
        int chg = h * 16 + ch;
        int el = ch * 16 + c;                              // e - h*256
        float bv_ = bias[h * 256 + el];
        #pragma unroll
        for (int r = 0; r < 4; ++r){
          int tk = wv * 16 + g * 4 + r;
          T[el * 65 + tk] = f2bf(acc[chg][r] + bv_);
        }
      }
      __syncthreads();
      #pragma unroll
      for (int it = 0; it < 8; ++it){
        int flat = it * 256 + tid;
        int el = flat >> 3, tg = flat & 7;
        u16 a0 = T[el*65 + tg*8 + 0], a1 = T[el*65 + tg*8 + 1];
        u16 a2 = T[el*65 + tg*8 + 2], a3 = T[el*65 + tg*8 + 3];
        u16 a4 = T[el*65 + tg*8 + 4], a5 = T[el*65 + tg*8 + 5];
        u16 a6 = T[el*65 + tg*8 + 6], a7 = T[el*65 + tg*8 + 7];
        int4 p;
        p.x = (int)((u32)a0 | ((u32)a1 << 16));
        p.y = (int)((u32)a2 | ((u32)a3 << 16));
        p.z = (int)((u32)a4 | ((u32)a5 << 16));
        p.w = (int)((u32)a6 | ((u32)a7 << 16));
        *(int4*)(Vtb + vbase + (size_t)(h * 256 + el) * Km + tg * 8) = p;
      }
    }
  } else {
    #pragma unroll
    for (int ch = 0; ch < 32; ++ch){
      int col = ch * 16 + c;
      float bv_ = bias[col];
      #pragma unroll
      for (int r = 0; r < 4; ++r){
        int tok = xt * 64 + wv * 16 + g * 4 + r;
        float val = (acc[ch][r] + bv_) * scale;
        size_t idx = (size_t)(tokOff + tok) * 512 + col;
        if (widx == 3)      outF[idx] = val;            // Oproj fp32 (relu later)
        else if (widx == 0) Qb[idx] = f2bf(val);        // Q pre-scaled
        else                Kb[idx] = f2bf(val);
      }
    }
  }
}

// ---------------- kernel 3: cross attention ----------------
// grid (16, 32 batch, 3 modality), block 256 = 4 waves, each wave one 16-row q-tile.
// Per source n != m: S = Q*K^T (exp, fp32 row-sum), P bf16 via per-wave LDS scratch, PV MFMA.
// srcI==0: d_out += msg1 (Oproj already there). srcI==1: d_out = relu(d_out + msg2).
__global__ void __launch_bounds__(256) attn_k(
    const u16* __restrict__ Qb, const u16* __restrict__ Kb,
    const u16* __restrict__ Vtb, float* __restrict__ outF)
{
  const int m = blockIdx.z, y = blockIdx.y, xt = blockIdx.x;
  const int Km = (m == 0) ? 1024 : (m == 1) ? 768 : 512;
  if (xt * 64 >= Km) return;
  const int tokOffM = (m == 0) ? 0 : (m == 1) ? 32768 : 57344;

  __shared__ __align__(16) char smem[32768 + 5120];  // KV tile (32KB) | P scratch 4x[16][40]
  const int tid = threadIdx.x, wv = tid >> 6, l = tid & 63, g = l >> 4, c = l & 15;
  u16* P = (u16*)(smem + 32768) + wv * 640;

  const int qbase = tokOffM + y * Km + xt * 64 + wv * 16;  // global row of wave's first q
  vbf8 qf[16];
  {
    const u16* qp = Qb + (size_t)(qbase + c) * 512 + g * 8;
    #pragma unroll
    for (int ch = 0; ch < 16; ++ch) qf[ch] = *(const vbf8*)(qp + ch * 32);
  }

  vf4 acc[32];
  #pragma unroll
  for (int ch = 0; ch < 32; ++ch) acc[ch] = (vf4){0.f, 0.f, 0.f, 0.f};
  float lp[4] = {0.f, 0.f, 0.f, 0.f};

  for (int srcI = 0; srcI < 2; ++srcI){
    const int n = (srcI == 0) ? ((m == 0) ? 1 : 0) : ((m == 2) ? 1 : 2);
    const int Kn = (n == 0) ? 1024 : (n == 1) ? 768 : 512;
    const int tokOffN = (n == 0) ? 0 : (n == 1) ? 32768 : 57344;
    const size_t kBase = (size_t)(tokOffN + y * Kn) * 512;
    const size_t vBase = (size_t)tokOffN * 512 + (size_t)y * 512 * Kn;

    for (int kt = 0; kt < Kn / 32; ++kt){
      __syncthreads();                       // protect prior PV reads from restage
      // stage K tile [32 keys][512 d], XOR-swizzled 16B slots
      #pragma unroll
      for (int it = 0; it < 8; ++it){
        int flat = it * 256 + tid;
        int key = flat >> 6, sl = flat & 63;
        int4 v = *(const int4*)(Kb + kBase + (size_t)(kt * 32 + key) * 512 + sl * 8);
        *(int4*)(smem + key * 1024 + ((sl * 16) ^ ((key & 7) << 4))) = v;
      }
      __syncthreads();
      // S = Q*K^T (logits; scale pre-folded into Q)
      vf4 s0 = (vf4){0.f,0.f,0.f,0.f}, s1 = (vf4){0.f,0.f,0.f,0.f};
      #pragma unroll
      for (int ch = 0; ch < 16; ++ch){
        vbf8 k0 = *(const vbf8*)(smem + c * 1024 + ((ch * 64 + g * 16) ^ ((c & 7) << 4)));
        vbf8 k1 = *(const vbf8*)(smem + (16 + c) * 1024 + ((ch * 64 + g * 16) ^ ((c & 7) << 4)));
        s0 = MFMA(qf[ch], k0, s0);
        s1 = MFMA(qf[ch], k1, s1);
      }
      // p = exp(s); accumulate fp32 row-sums; stash P (bf16) for PV A-frag transpose
      #pragma unroll
      for (int r = 0; r < 4; ++r){
        float e0 = __expf(s0[r]);
        float e1 = __expf(s1[r]);
        lp[r] += e0 + e1;
        P[(g * 4 + r) * 40 + c]      = f2bf(e0);
        P[(g * 4 + r) * 40 + 16 + c] = f2bf(e1);
      }
      __syncthreads();                       // all waves done reading K tile
      // stage Vt tile [512 d][32 keys], XOR-swizzled
      #pragma unroll
      for (int it = 0; it < 8; ++it){
        int flat = it * 256 + tid;
        int e = flat >> 2, sl = flat & 3;
        int4 v = *(const int4*)(Vtb + vBase + (size_t)e * Kn + kt * 32 + sl * 8);
        *(int4*)(smem + e * 64 + ((sl * 16) ^ ((e & 3) << 4))) = v;
      }
      __syncthreads();
      vbf8 pa = *(const vbf8*)(P + c * 40 + g * 8);   // A-frag: P[q=c][keys g*8..+7]
      #pragma unroll
      for (int ch = 0; ch < 32; ++ch){
        int e = ch * 16 + c;
        vbf8 vfg = *(const vbf8*)(smem + e * 64 + ((g * 16) ^ ((e & 3) << 4)));
        acc[ch] = MFMA(pa, vfg, acc[ch]);
      }
    }
    // finalize source: row-sum reduce across the 16 key-lanes, merge into d_out
    float w_[4];
    #pragma unroll
    for (int r = 0; r < 4; ++r){
      float v = lp[r];
      v += __shfl_xor(v, 1); v += __shfl_xor(v, 2);
      v += __shfl_xor(v, 4); v += __shfl_xor(v, 8);
      w_[r] = 1.0f / v;
      lp[r] = 0.f;
    }
    #pragma unroll
    for (int ch = 0; ch < 32; ++ch){
      int col = ch * 16 + c;
      #pragma unroll
      for (int r = 0; r < 4; ++r){
        size_t idx = (size_t)(qbase + g * 4 + r) * 512 + col;
        float v = outF[idx] + acc[ch][r] * w_[r];
        outF[idx] = (srcI == 1) ? fmaxf(v, 0.f) : v;
        acc[ch][r] = 0.f;
      }
    }
  }
}

// ---------------- host launcher ----------------
extern "C" void kernel_launch(void* const* d_in, const int* in_sizes, int n_in,
                              void* d_out, int out_size, void* d_ws, size_t ws_size,
                              hipStream_t stream){
  const float* E0 = (const float*)d_in[0];
  const float* E1 = (const float*)d_in[1];
  const float* E2 = (const float*)d_in[2];
  const float* Wq = (const float*)d_in[3];
  const float* bq = (const float*)d_in[4];
  const float* Wk = (const float*)d_in[5];
  const float* bk = (const float*)d_in[6];
  const float* Wv = (const float*)d_in[7];
  const float* bv = (const float*)d_in[8];
  const float* Wo = (const float*)d_in[9];
  const float* bo = (const float*)d_in[10];
  float* outF = (float*)d_out;

  char* ws = (char*)d_ws;
  const size_t SZ = 75497472u;                 // 73728*512*2 bytes (bf16)
  u16* Wbf = (u16*)ws;                         // 2 MB
  u16* Qb  = (u16*)(ws + (size_t)(2u << 20));
  u16* Kb  = (u16*)(ws + (size_t)(2u << 20) + SZ);
  u16* Vtb = (u16*)(ws + (size_t)(2u << 20) + 2 * SZ);
  // requires ws_size >= 2MB + 3*72MB = ~228.6MB

  wconv_k<<<dim3(1024), dim3(256), 0, stream>>>(Wq, Wk, Wv, Wo, Wbf);
  proj_k<<<dim3(512, 4, 3), dim3(256), 0, stream>>>(E0, E1, E2, Wbf, bq, bk, bv, bo,
                                                    Qb, Kb, Vtb, outF);
  attn_k<<<dim3(16, 32, 3), dim3(256), 0, stream>>>(Qb, Kb, Vtb, outF);
}